// Round 15
// baseline (513.944 us; speedup 1.0000x reference)
//
#include <hip/hip_runtime.h>
#include <math.h>

#define HID 64
#define NLAY 5
#define NFF 512

typedef __attribute__((ext_vector_type(8))) short bf16x8;
typedef __attribute__((ext_vector_type(4))) float f32x4;

// fp32 -> bf16 (round-to-nearest-even), bit trick; and back.
__device__ __forceinline__ unsigned short f2bf(float x) {
  unsigned int b = __float_as_uint(x);
  b += 0x7FFFu + ((b >> 16) & 1u);
  return (unsigned short)(b >> 16);
}
__device__ __forceinline__ float bf2f(unsigned short u) {
  return __uint_as_float((unsigned int)u << 16);
}

// One fused prep dispatch:
//  blocks 0..4   : Wl[l] = edge_emb_w @ edge_lin_w[l]
//  blocks 5..20  : split w1 into bf16 hi/lo MFMA B-fragments
//  blocks 21..35 : split rel/root/res into bf16 hi/lo fragments
__global__ void prep_all_kernel(const float* __restrict__ edge_emb_w,
                                const float* __restrict__ edge_lin_w,
                                const float* __restrict__ w1,
                                const float* __restrict__ rel_w,
                                const float* __restrict__ root_w,
                                const float* __restrict__ res_w,
                                float* __restrict__ Wl,
                                unsigned short* __restrict__ w1bhi,
                                unsigned short* __restrict__ w1blo,
                                unsigned short* __restrict__ nwhi,
                                unsigned short* __restrict__ nwlo) {
  int bid = blockIdx.x;
  int tid = threadIdx.x;
  if (bid < 5) {
    int j = tid >> 6;
    int d = tid & 63;
    const float* ew = edge_emb_w + j * HID;
    const float* lw = edge_lin_w + bid * HID * HID;
    float acc = 0.f;
#pragma unroll
    for (int k = 0; k < HID; ++k) acc = fmaf(ew[k], lw[k * HID + d], acc);
    Wl[(bid * 4 + j) * HID + d] = acc;
  } else if (bid < 21) {
    int t = (bid - 5) * 256 + tid;
    int f = t >> 6;
    int l = t & 63;
    int kt = f >> 5;
    int nt = f & 31;
    int krow = kt * 32 + (l >> 4) * 8;
    int col = nt * 16 + (l & 15);
#pragma unroll
    for (int j = 0; j < 8; ++j) {
      float v = w1[(size_t)(krow + j) * NFF + col];
      unsigned short hi = f2bf(v);
      unsigned short lo = f2bf(v - bf2f(hi));
      w1bhi[(size_t)t * 8 + j] = hi;
      w1blo[(size_t)t * 8 + j] = lo;
    }
  } else {
    int mi = bid - 21;
    int layer = mi / 3, mat = mi % 3;
    const float* W = (mat == 0 ? rel_w : (mat == 1 ? root_w : res_w)) +
                     (size_t)layer * HID * HID;
#pragma unroll
    for (int half = 0; half < 2; ++half) {
      int t = half * 256 + tid;
      int f = t >> 6, l = t & 63;
      int kt = f >> 2, nt = f & 3;
      int krow = kt * 32 + (l >> 4) * 8;
      int col = nt * 16 + (l & 15);
#pragma unroll
      for (int j = 0; j < 8; ++j) {
        float v = W[(size_t)(krow + j) * HID + col];
        unsigned short hi = f2bf(v);
        unsigned short lo = f2bf(v - bf2f(hi));
        size_t off = (((size_t)mi * 8 + f) * 64 + l) * 8 + j;
        nwhi[off] = hi;
        nwlo[off] = lo;
      }
    }
  }
}

// h[n][d] = vert_emb[x[n]][d]; bf16 shadow; fused deg zeroing.
__global__ void embed_kernel(const int* __restrict__ x,
                             const float* __restrict__ vert_emb,
                             float* __restrict__ h,
                             unsigned short* __restrict__ h16,
                             int* __restrict__ deg, int n) {
  int idx = blockIdx.x * blockDim.x + threadIdx.x;
  if (idx >= n * HID) return;
  int node = idx >> 6;
  int d = idx & 63;
  float v = vert_emb[x[node] * HID + d];
  h[idx] = v;
  h16[idx] = f2bf(v);
  if (d == 0) deg[node] = 0;
}

// ---- CSR build ----

__global__ void hist_kernel(const int* __restrict__ dst, int* __restrict__ deg, int E) {
  int e = blockIdx.x * blockDim.x + threadIdx.x;
  if (e < E) atomicAdd(&deg[dst[e]], 1);
}

__global__ void bsum_kernel(const int* __restrict__ deg, int* __restrict__ bsum, int n) {
  __shared__ int s[256];
  int t = threadIdx.x;
  int i = blockIdx.x * 256 + t;
  s[t] = (i < n) ? deg[i] : 0;
  __syncthreads();
#pragma unroll
  for (int off = 128; off > 0; off >>= 1) {
    if (t < off) s[t] += s[t + off];
    __syncthreads();
  }
  if (t == 0) bsum[blockIdx.x] = s[0];
}

__global__ void bscan_kernel(const int* __restrict__ bsum, int* __restrict__ boff, int nb) {
  __shared__ int s[256];
  int t = threadIdx.x;
  int v = (t < nb) ? bsum[t] : 0;
  s[t] = v;
  __syncthreads();
#pragma unroll
  for (int off = 1; off < 256; off <<= 1) {
    int u = (t >= off) ? s[t - off] : 0;
    __syncthreads();
    s[t] += u;
    __syncthreads();
  }
  if (t < nb) boff[t] = s[t] - v;   // exclusive
}

__global__ void scan3_kernel(const int* __restrict__ deg, const int* __restrict__ boff,
                             int* __restrict__ row_ptr, int* __restrict__ cursor, int n) {
  __shared__ int s[256];
  int t = threadIdx.x;
  int i = blockIdx.x * 256 + t;
  int v = (i < n) ? deg[i] : 0;
  s[t] = v;
  __syncthreads();
#pragma unroll
  for (int off = 1; off < 256; off <<= 1) {
    int u = (t >= off) ? s[t - off] : 0;
    __syncthreads();
    s[t] += u;
    __syncthreads();
  }
  if (i < n) {
    int excl = boff[blockIdx.x] + s[t] - v;
    row_ptr[i] = excl;
    cursor[i] = excl;
    if (i == n - 1) row_ptr[n] = excl + v;
  }
}

// Packed 32B record per edge: csr2[2*pos] = ea, csr2[2*pos+1].x = src bits.
__global__ void scatter_kernel(const int* __restrict__ src,
                               const int* __restrict__ dst,
                               const float4* __restrict__ edge_attr,
                               int* __restrict__ cursor,
                               float4* __restrict__ csr2, int E) {
  int e = blockIdx.x * blockDim.x + threadIdx.x;
  if (e >= E) return;
  int pos = atomicAdd(&cursor[dst[e]], 1);
  csr2[(size_t)2 * pos] = edge_attr[e];
  float4 m;
  m.x = __int_as_float(src[e]);
  m.y = 0.f; m.z = 0.f; m.w = 0.f;
  csr2[(size_t)2 * pos + 1] = m;
}

// ---- deep-pipeline gather: 1 wave per dst node, lane = dim ----
// r14 diagnosis: VGPR_Count=36 -> compiler sank loads, serializing TWO chained
// memory latencies per edge (uniform src load -> dependent h16 gather).
// Fix: (1) vector-preload up to 64 srcs with ONE per-lane strided load, then
// readlane (SALU) -> chain depth 1 load/edge; (2) explicit register double-
// buffering in 8-edge chunks (prefetch c+1 before consuming c); (3) LB(256,4)
// -> 128 VGPR budget so the ~100-reg pipeline fits.
#define GLOAD_CHUNK(HH, EE, c)                                            \
  {                                                                       \
    int cbase = 8 * (c);                                                  \
    _Pragma("unroll")                                                     \
    for (int u = 0; u < 8; ++u) {                                         \
      int idx = cbase + u;                                                \
      int cl = (idx < bcnt) ? idx : 0;                                    \
      int su = __builtin_amdgcn_readlane(srcv, cl);                       \
      HH[u] = bf2f(h16[(size_t)su * HID + d]);                            \
      float4 ev = csr2[(size_t)2 * (blk + cl)];                           \
      if (idx >= bcnt) { ev.x = 0.f; ev.y = 0.f; ev.z = 0.f; ev.w = 0.f; } \
      EE[u] = ev;                                                         \
    }                                                                     \
  }

#define GCONSUME_CHUNK(HH, EE)                                            \
  {                                                                       \
    _Pragma("unroll")                                                     \
    for (int u = 0; u < 8; ++u) {                                         \
      P0 = fmaf(EE[u].x, HH[u], P0);                                      \
      P1 = fmaf(EE[u].y, HH[u], P1);                                      \
      P2 = fmaf(EE[u].z, HH[u], P2);                                      \
      P3 = fmaf(EE[u].w, HH[u], P3);                                      \
    }                                                                     \
  }

__global__ __launch_bounds__(256, 4)
void gather_kernel(const int* __restrict__ row_ptr,
                   const float4* __restrict__ csr2,
                   const float* __restrict__ Wl,   // this layer's [4][64]
                   const unsigned short* __restrict__ h16,
                   float* __restrict__ agg, int n) {
  int wid = threadIdx.x >> 6;
  int d = threadIdx.x & 63;
  int node = blockIdx.x * 4 + wid;
  if (node >= n) return;
  int beg = __builtin_amdgcn_readfirstlane(row_ptr[node]);
  int end = __builtin_amdgcn_readfirstlane(row_ptr[node + 1]);
  const int* csri = (const int*)csr2;
  float P0 = 0.f, P1 = 0.f, P2 = 0.f, P3 = 0.f;
  for (int blk = beg; blk < end; blk += 64) {
    int bcnt = end - blk;
    if (bcnt > 64) bcnt = 64;
    // one per-lane strided load covers up to 64 src indices (stride 32B);
    // these lines are re-read sequentially by the ee loads -> L1-hot.
    int li = (d < bcnt) ? d : bcnt - 1;
    int srcv = csri[((size_t)2 * (blk + li) + 1) * 4];
    int nch = (bcnt + 7) >> 3;
    float hhA[8], hhB[8];
    float4 eeA[8], eeB[8];
    GLOAD_CHUNK(hhA, eeA, 0)
    int c = 0;
    while (c < nch) {
      if (c + 1 < nch) {
        GLOAD_CHUNK(hhB, eeB, c + 1)
        GCONSUME_CHUNK(hhA, eeA)
        ++c;
        if (c + 1 < nch) { GLOAD_CHUNK(hhA, eeA, c + 1) }
        GCONSUME_CHUNK(hhB, eeB)
        ++c;
      } else {
        GCONSUME_CHUNK(hhA, eeA)
        ++c;
      }
    }
  }
  float w0 = Wl[d], w1_ = Wl[HID + d], w2_ = Wl[2 * HID + d], w3_ = Wl[3 * HID + d];
  float acc = fmaf(P3, w3_, fmaf(P2, w2_, fmaf(P1, w1_, P0 * w0)));
  agg[(size_t)node * HID + d] = acc;
}

// ---- MFMA node layer (r13-validated): hn = relu(agg@rel + b + h@root) + h@res ----
__global__ __launch_bounds__(256, 4)
void node_mfma_kernel(const float* __restrict__ h,
                      const unsigned short* __restrict__ h16,
                      const float* __restrict__ agg,
                      const unsigned short* __restrict__ nwhi,
                      const unsigned short* __restrict__ nwlo,
                      const float* __restrict__ rel_b,
                      float* __restrict__ hn,
                      unsigned short* __restrict__ hn16, int n) {
  int tid = threadIdx.x;
  int w = tid >> 6;
  int l = tid & 63;
  int q = l & 15;
  int g = l >> 4;
  int base = blockIdx.x * 16;
  int node = base + q;
  if (node >= n) node = n - 1;   // clamp; stores guarded
  bf16x8 aghi[2], aglo[2], ahhi[2], ahlo[2];
#pragma unroll
  for (int kt = 0; kt < 2; ++kt) {
    int koff = kt * 32 + g * 8;
    const float* ap = agg + (size_t)node * HID + koff;
    const float* hp = h + (size_t)node * HID + koff;
    ahhi[kt] = *(const bf16x8*)(h16 + (size_t)node * HID + koff);
#pragma unroll
    for (int j = 0; j < 8; ++j) {
      float av = ap[j];
      unsigned short hi = f2bf(av);
      aghi[kt][j] = (short)hi;
      aglo[kt][j] = (short)f2bf(av - bf2f(hi));
      float r = hp[j] - bf2f((unsigned short)ahhi[kt][j]);
      ahlo[kt][j] = (short)f2bf(r);
    }
  }
  f32x4 aR = {0.f, 0.f, 0.f, 0.f};
  f32x4 aO = {0.f, 0.f, 0.f, 0.f};
  f32x4 aS = {0.f, 0.f, 0.f, 0.f};
#pragma unroll
  for (int kt = 0; kt < 2; ++kt) {
    int f = kt * 4 + w;
    const bf16x8* bRh = (const bf16x8*)(nwhi + (((size_t)0 * 8 + f) * 64 + l) * 8);
    const bf16x8* bRl = (const bf16x8*)(nwlo + (((size_t)0 * 8 + f) * 64 + l) * 8);
    const bf16x8* bOh = (const bf16x8*)(nwhi + (((size_t)1 * 8 + f) * 64 + l) * 8);
    const bf16x8* bOl = (const bf16x8*)(nwlo + (((size_t)1 * 8 + f) * 64 + l) * 8);
    const bf16x8* bSh = (const bf16x8*)(nwhi + (((size_t)2 * 8 + f) * 64 + l) * 8);
    const bf16x8* bSl = (const bf16x8*)(nwlo + (((size_t)2 * 8 + f) * 64 + l) * 8);
    aR = __builtin_amdgcn_mfma_f32_16x16x32_bf16(aglo[kt], *bRh, aR, 0, 0, 0);
    aR = __builtin_amdgcn_mfma_f32_16x16x32_bf16(aghi[kt], *bRl, aR, 0, 0, 0);
    aR = __builtin_amdgcn_mfma_f32_16x16x32_bf16(aghi[kt], *bRh, aR, 0, 0, 0);
    aO = __builtin_amdgcn_mfma_f32_16x16x32_bf16(ahlo[kt], *bOh, aO, 0, 0, 0);
    aO = __builtin_amdgcn_mfma_f32_16x16x32_bf16(ahhi[kt], *bOl, aO, 0, 0, 0);
    aO = __builtin_amdgcn_mfma_f32_16x16x32_bf16(ahhi[kt], *bOh, aO, 0, 0, 0);
    aS = __builtin_amdgcn_mfma_f32_16x16x32_bf16(ahlo[kt], *bSh, aS, 0, 0, 0);
    aS = __builtin_amdgcn_mfma_f32_16x16x32_bf16(ahhi[kt], *bSl, aS, 0, 0, 0);
    aS = __builtin_amdgcn_mfma_f32_16x16x32_bf16(ahhi[kt], *bSh, aS, 0, 0, 0);
  }
  int col = w * 16 + q;
  float bd = rel_b[col];
#pragma unroll
  for (int r = 0; r < 4; ++r) {
    int nd = base + g * 4 + r;
    if (nd < n) {
      float v = fmaxf(aR[r] + aO[r] + bd, 0.f) + aS[r];
      hn[(size_t)nd * HID + col] = v;
      hn16[(size_t)nd * HID + col] = f2bf(v);
    }
  }
}

// ---- MFMA head (r12-validated) ----
__global__ __launch_bounds__(256, 4)
void head_kernel(const float* __restrict__ h,
                 const unsigned short* __restrict__ h16,
                 const unsigned short* __restrict__ w1bhi,
                 const unsigned short* __restrict__ w1blo,
                 const float* __restrict__ b1,
                 const float* __restrict__ w2,
                 const float* __restrict__ b2,
                 float* __restrict__ out, int n) {
  __shared__ float red[4][16];
  int tid = threadIdx.x;
  int w = tid >> 6;
  int l = tid & 63;
  int row = l & 15;
  int g = l >> 4;
  int base = blockIdx.x * 16;
  int node = base + row;
  if (node >= n) node = n - 1;
  f32x4 acc[8];
#pragma unroll
  for (int t = 0; t < 8; ++t) acc[t] = (f32x4){0.f, 0.f, 0.f, 0.f};
#pragma unroll
  for (int kt = 0; kt < 2; ++kt) {
    int koff = kt * 32 + g * 8;
    bf16x8 ahi = *(const bf16x8*)(h16 + (size_t)node * HID + koff);
    const float* hp = h + (size_t)node * HID + koff;
    bf16x8 alo;
#pragma unroll
    for (int j = 0; j < 8; ++j) {
      float r = hp[j] - bf2f((unsigned short)ahi[j]);
      alo[j] = (short)f2bf(r);
    }
#pragma unroll
    for (int t = 0; t < 8; ++t) {
      int f = kt * 32 + w * 8 + t;
      bf16x8 bhi = *(const bf16x8*)(w1bhi + (size_t)f * 512 + l * 8);
      bf16x8 blo = *(const bf16x8*)(w1blo + (size_t)f * 512 + l * 8);
      acc[t] = __builtin_amdgcn_mfma_f32_16x16x32_bf16(alo, bhi, acc[t], 0, 0, 0);
      acc[t] = __builtin_amdgcn_mfma_f32_16x16x32_bf16(ahi, blo, acc[t], 0, 0, 0);
      acc[t] = __builtin_amdgcn_mfma_f32_16x16x32_bf16(ahi, bhi, acc[t], 0, 0, 0);
    }
  }
  float s0 = 0.f, s1 = 0.f, s2 = 0.f, s3 = 0.f;
#pragma unroll
  for (int t = 0; t < 8; ++t) {
    int ff = (w * 8 + t) * 16 + row;
    float bb = b1[ff];
    float ww = w2[ff];
    float xv, gl;
    xv = acc[t][0] + bb; gl = 0.5f * xv * (1.f + erff(xv * 0.70710678118654752f)); s0 = fmaf(gl, ww, s0);
    xv = acc[t][1] + bb; gl = 0.5f * xv * (1.f + erff(xv * 0.70710678118654752f)); s1 = fmaf(gl, ww, s1);
    xv = acc[t][2] + bb; gl = 0.5f * xv * (1.f + erff(xv * 0.70710678118654752f)); s2 = fmaf(gl, ww, s2);
    xv = acc[t][3] + bb; gl = 0.5f * xv * (1.f + erff(xv * 0.70710678118654752f)); s3 = fmaf(gl, ww, s3);
  }
#pragma unroll
  for (int off = 1; off < 16; off <<= 1) {
    s0 += __shfl_xor(s0, off);
    s1 += __shfl_xor(s1, off);
    s2 += __shfl_xor(s2, off);
    s3 += __shfl_xor(s3, off);
  }
  if ((l & 15) == 0) {
    red[w][g * 4 + 0] = s0;
    red[w][g * 4 + 1] = s1;
    red[w][g * 4 + 2] = s2;
    red[w][g * 4 + 3] = s3;
  }
  __syncthreads();
  if (tid < 16 && base + tid < n)
    out[base + tid] = red[0][tid] + red[1][tid] + red[2][tid] + red[3][tid] + b2[0];
}

extern "C" void kernel_launch(void* const* d_in, const int* in_sizes, int n_in,
                              void* d_out, int out_size, void* d_ws, size_t ws_size,
                              hipStream_t stream) {
  const int*   x          = (const int*)d_in[0];
  const int*   edge_index = (const int*)d_in[1];
  const float* edge_attr  = (const float*)d_in[2];
  const float* vert_emb   = (const float*)d_in[3];
  const float* edge_emb_w = (const float*)d_in[4];
  const float* edge_lin_w = (const float*)d_in[5];
  const float* rel_w      = (const float*)d_in[6];
  const float* rel_b      = (const float*)d_in[7];
  const float* root_w     = (const float*)d_in[8];
  const float* res_w      = (const float*)d_in[9];
  const float* w1         = (const float*)d_in[10];
  const float* b1         = (const float*)d_in[11];
  const float* w2         = (const float*)d_in[12];
  const float* b2         = (const float*)d_in[13];

  const int n = in_sizes[0];
  const int E = in_sizes[2] / 4;
  const int* src = edge_index;
  const int* dst = edge_index + E;
  const int nb = (n + 255) / 256;

  // workspace layout:
  //   Wl[2048] f | hA[n*64] f | hB[n*64] f | agg[n*64] f | csr2[2E] float4 |
  //   row_ptr[n+1] | cursor[n] | deg[n] | bsum[256] | boff[256] (ints) |
  //   (16B-align) w1bhi[32768] | w1blo[32768] | nwhi[61440] | nwlo[61440] |
  //   h16A[n*64] | h16B[n*64] (u16)
  float* ws   = (float*)d_ws;
  float* Wl   = ws;
  float* hA   = ws + 2048;
  float* hB   = hA + (size_t)n * HID;
  float* agg  = hB + (size_t)n * HID;
  float4* csr2 = (float4*)(agg + (size_t)n * HID);
  int* row_ptr = (int*)(csr2 + (size_t)2 * E);
  int* cursor  = row_ptr + (n + 1);
  int* deg     = cursor + n;
  int* bsum    = deg + n;
  int* boff    = bsum + 256;
  unsigned short* w1bhi = (unsigned short*)(((size_t)(boff + 256) + 15) & ~(size_t)15);
  unsigned short* w1blo = w1bhi + 64 * 512;
  unsigned short* nwhi  = w1blo + 64 * 512;
  unsigned short* nwlo  = nwhi + NLAY * 3 * 4096;
  unsigned short* h16A  = nwlo + NLAY * 3 * 4096;
  unsigned short* h16B  = h16A + (size_t)n * HID;

  prep_all_kernel<<<dim3(36), dim3(256), 0, stream>>>(
      edge_emb_w, edge_lin_w, w1, rel_w, root_w, res_w,
      Wl, w1bhi, w1blo, nwhi, nwlo);

  int totalHD = n * HID;
  embed_kernel<<<dim3((totalHD + 255) / 256), dim3(256), 0, stream>>>(
      x, vert_emb, hA, h16A, deg, n);

  hist_kernel<<<dim3((E + 255) / 256), dim3(256), 0, stream>>>(dst, deg, E);
  bsum_kernel<<<dim3(nb), dim3(256), 0, stream>>>(deg, bsum, n);
  bscan_kernel<<<dim3(1), dim3(256), 0, stream>>>(bsum, boff, nb);
  scan3_kernel<<<dim3(nb), dim3(256), 0, stream>>>(deg, boff, row_ptr, cursor, n);
  scatter_kernel<<<dim3((E + 255) / 256), dim3(256), 0, stream>>>(
      src, dst, (const float4*)edge_attr, cursor, csr2, E);

  float* hc = hA;
  float* hx = hB;
  unsigned short* h16c = h16A;
  unsigned short* h16x = h16B;
  for (int l = 0; l < NLAY; ++l) {
    gather_kernel<<<dim3((n + 3) / 4), dim3(256), 0, stream>>>(
        row_ptr, csr2, Wl + l * 4 * HID, h16c, agg, n);
    node_mfma_kernel<<<dim3((n + 15) / 16), dim3(256), 0, stream>>>(
        hc, h16c, agg, nwhi + (size_t)l * 3 * 4096, nwlo + (size_t)l * 3 * 4096,
        rel_b + l * HID, hx, h16x, n);
    float* t = hc; hc = hx; hx = t;
    unsigned short* t16 = h16c; h16c = h16x; h16x = t16;
  }

  head_kernel<<<dim3((n + 15) / 16), dim3(256), 0, stream>>>(
      hc, h16c, w1bhi, w1blo, b1, w2, b2, (float*)d_out, n);
}

// Round 16
// 419.186 us; speedup vs baseline: 1.2261x; 1.2261x over previous
//
#include <hip/hip_runtime.h>
#include <math.h>

#define HID 64
#define NLAY 5
#define NFF 512

typedef __attribute__((ext_vector_type(8))) short bf16x8;
typedef __attribute__((ext_vector_type(4))) float f32x4;

// fp32 -> bf16 (round-to-nearest-even), bit trick; and back.
__device__ __forceinline__ unsigned short f2bf(float x) {
  unsigned int b = __float_as_uint(x);
  b += 0x7FFFu + ((b >> 16) & 1u);
  return (unsigned short)(b >> 16);
}
__device__ __forceinline__ float bf2f(unsigned short u) {
  return __uint_as_float((unsigned int)u << 16);
}

// One fused prep dispatch:
//  blocks 0..4   : Wl[l] = edge_emb_w @ edge_lin_w[l]
//  blocks 5..20  : split w1 into bf16 hi/lo MFMA B-fragments
//  blocks 21..35 : split rel/root/res into bf16 hi/lo fragments
__global__ void prep_all_kernel(const float* __restrict__ edge_emb_w,
                                const float* __restrict__ edge_lin_w,
                                const float* __restrict__ w1,
                                const float* __restrict__ rel_w,
                                const float* __restrict__ root_w,
                                const float* __restrict__ res_w,
                                float* __restrict__ Wl,
                                unsigned short* __restrict__ w1bhi,
                                unsigned short* __restrict__ w1blo,
                                unsigned short* __restrict__ nwhi,
                                unsigned short* __restrict__ nwlo) {
  int bid = blockIdx.x;
  int tid = threadIdx.x;
  if (bid < 5) {
    int j = tid >> 6;
    int d = tid & 63;
    const float* ew = edge_emb_w + j * HID;
    const float* lw = edge_lin_w + bid * HID * HID;
    float acc = 0.f;
#pragma unroll
    for (int k = 0; k < HID; ++k) acc = fmaf(ew[k], lw[k * HID + d], acc);
    Wl[(bid * 4 + j) * HID + d] = acc;
  } else if (bid < 21) {
    int t = (bid - 5) * 256 + tid;
    int f = t >> 6;
    int l = t & 63;
    int kt = f >> 5;
    int nt = f & 31;
    int krow = kt * 32 + (l >> 4) * 8;
    int col = nt * 16 + (l & 15);
#pragma unroll
    for (int j = 0; j < 8; ++j) {
      float v = w1[(size_t)(krow + j) * NFF + col];
      unsigned short hi = f2bf(v);
      unsigned short lo = f2bf(v - bf2f(hi));
      w1bhi[(size_t)t * 8 + j] = hi;
      w1blo[(size_t)t * 8 + j] = lo;
    }
  } else {
    int mi = bid - 21;
    int layer = mi / 3, mat = mi % 3;
    const float* W = (mat == 0 ? rel_w : (mat == 1 ? root_w : res_w)) +
                     (size_t)layer * HID * HID;
#pragma unroll
    for (int half = 0; half < 2; ++half) {
      int t = half * 256 + tid;
      int f = t >> 6, l = t & 63;
      int kt = f >> 2, nt = f & 3;
      int krow = kt * 32 + (l >> 4) * 8;
      int col = nt * 16 + (l & 15);
#pragma unroll
      for (int j = 0; j < 8; ++j) {
        float v = W[(size_t)(krow + j) * HID + col];
        unsigned short hi = f2bf(v);
        unsigned short lo = f2bf(v - bf2f(hi));
        size_t off = (((size_t)mi * 8 + f) * 64 + l) * 8 + j;
        nwhi[off] = hi;
        nwlo[off] = lo;
      }
    }
  }
}

// h[n][d] = vert_emb[x[n]][d]; bf16 shadow; fused deg zeroing.
__global__ void embed_kernel(const int* __restrict__ x,
                             const float* __restrict__ vert_emb,
                             float* __restrict__ h,
                             unsigned short* __restrict__ h16,
                             int* __restrict__ deg, int n) {
  int idx = blockIdx.x * blockDim.x + threadIdx.x;
  if (idx >= n * HID) return;
  int node = idx >> 6;
  int d = idx & 63;
  float v = vert_emb[x[node] * HID + d];
  h[idx] = v;
  h16[idx] = f2bf(v);
  if (d == 0) deg[node] = 0;
}

// ---- CSR build ----

__global__ void hist_kernel(const int* __restrict__ dst, int* __restrict__ deg, int E) {
  int e = blockIdx.x * blockDim.x + threadIdx.x;
  if (e < E) atomicAdd(&deg[dst[e]], 1);
}

__global__ void bsum_kernel(const int* __restrict__ deg, int* __restrict__ bsum, int n) {
  __shared__ int s[256];
  int t = threadIdx.x;
  int i = blockIdx.x * 256 + t;
  s[t] = (i < n) ? deg[i] : 0;
  __syncthreads();
#pragma unroll
  for (int off = 128; off > 0; off >>= 1) {
    if (t < off) s[t] += s[t + off];
    __syncthreads();
  }
  if (t == 0) bsum[blockIdx.x] = s[0];
}

__global__ void bscan_kernel(const int* __restrict__ bsum, int* __restrict__ boff, int nb) {
  __shared__ int s[256];
  int t = threadIdx.x;
  int v = (t < nb) ? bsum[t] : 0;
  s[t] = v;
  __syncthreads();
#pragma unroll
  for (int off = 1; off < 256; off <<= 1) {
    int u = (t >= off) ? s[t - off] : 0;
    __syncthreads();
    s[t] += u;
    __syncthreads();
  }
  if (t < nb) boff[t] = s[t] - v;   // exclusive
}

__global__ void scan3_kernel(const int* __restrict__ deg, const int* __restrict__ boff,
                             int* __restrict__ row_ptr, int* __restrict__ cursor, int n) {
  __shared__ int s[256];
  int t = threadIdx.x;
  int i = blockIdx.x * 256 + t;
  int v = (i < n) ? deg[i] : 0;
  s[t] = v;
  __syncthreads();
#pragma unroll
  for (int off = 1; off < 256; off <<= 1) {
    int u = (t >= off) ? s[t - off] : 0;
    __syncthreads();
    s[t] += u;
    __syncthreads();
  }
  if (i < n) {
    int excl = boff[blockIdx.x] + s[t] - v;
    row_ptr[i] = excl;
    cursor[i] = excl;
    if (i == n - 1) row_ptr[n] = excl + v;
  }
}

// Packed 16B record per edge: {src:int, ea as 4xbf16, pad}.
// Halves scatter payload (25.6->12.8 MB) and the gather's sequential csr
// stream per layer; 4 records/64B line improves write-combining.
__global__ void scatter_kernel(const int* __restrict__ src,
                               const int* __restrict__ dst,
                               const float4* __restrict__ edge_attr,
                               int* __restrict__ cursor,
                               int4* __restrict__ csr4, int E) {
  int e = blockIdx.x * blockDim.x + threadIdx.x;
  if (e >= E) return;
  int pos = atomicAdd(&cursor[dst[e]], 1);
  float4 ea = edge_attr[e];
  int4 rec;
  rec.x = src[e];
  rec.y = (int)f2bf(ea.x) | ((int)f2bf(ea.y) << 16);
  rec.z = (int)f2bf(ea.z) | ((int)f2bf(ea.w) << 16);
  rec.w = 0;
  csr4[pos] = rec;
}

// ---- fused layer: gather (rank-4, bf16 payload) + MFMA node transform ----
// Gather is memory-system-bound (r13/r14/r15: three codegens, same time);
// the lever here is the halved record stream. Phase A: wave w gathers nodes
// base+4w..+3 into LDS sagg[16][65]. Phase B: MFMA node transform (r13-validated).
__global__ __launch_bounds__(256, 4)
void layer_fused_kernel(const int* __restrict__ row_ptr,
                        const int4* __restrict__ csr4,
                        const float* __restrict__ Wl,   // this layer's [4][64]
                        const float* __restrict__ h,
                        const unsigned short* __restrict__ h16,
                        const unsigned short* __restrict__ nwhi,  // this layer
                        const unsigned short* __restrict__ nwlo,
                        const float* __restrict__ rel_b,          // this layer
                        float* __restrict__ hn,
                        unsigned short* __restrict__ hn16, int n) {
  __shared__ float sagg[16][65];
  int tid = threadIdx.x;
  int w = tid >> 6;
  int d = tid & 63;
  int base = blockIdx.x * 16;
  // ---- Phase A: gather ----
  float w0 = Wl[d], w1_ = Wl[HID + d], w2_ = Wl[2 * HID + d], w3_ = Wl[3 * HID + d];
  for (int i = 0; i < 4; ++i) {
    int node = base + w * 4 + i;
    float P0 = 0.f, P1 = 0.f, P2 = 0.f, P3 = 0.f;
    if (node < n) {
      int beg = __builtin_amdgcn_readfirstlane(row_ptr[node]);
      int end = __builtin_amdgcn_readfirstlane(row_ptr[node + 1]);
      int j = beg;
      for (; j + 16 <= end; j += 16) {
        int4 rr[16];
        float hh[16];
#pragma unroll
        for (int u = 0; u < 16; ++u) rr[u] = csr4[(size_t)(j + u)];
#pragma unroll
        for (int u = 0; u < 16; ++u)
          hh[u] = bf2f(h16[(size_t)rr[u].x * HID + d]);
#pragma unroll
        for (int u = 0; u < 16; ++u) {
          P0 = fmaf(bf2f((unsigned short)(rr[u].y & 0xFFFF)), hh[u], P0);
          P1 = fmaf(bf2f((unsigned short)((unsigned)rr[u].y >> 16)), hh[u], P1);
          P2 = fmaf(bf2f((unsigned short)(rr[u].z & 0xFFFF)), hh[u], P2);
          P3 = fmaf(bf2f((unsigned short)((unsigned)rr[u].z >> 16)), hh[u], P3);
        }
      }
      for (; j + 4 <= end; j += 4) {
        int4 rr[4];
        float hh[4];
#pragma unroll
        for (int u = 0; u < 4; ++u) rr[u] = csr4[(size_t)(j + u)];
#pragma unroll
        for (int u = 0; u < 4; ++u)
          hh[u] = bf2f(h16[(size_t)rr[u].x * HID + d]);
#pragma unroll
        for (int u = 0; u < 4; ++u) {
          P0 = fmaf(bf2f((unsigned short)(rr[u].y & 0xFFFF)), hh[u], P0);
          P1 = fmaf(bf2f((unsigned short)((unsigned)rr[u].y >> 16)), hh[u], P1);
          P2 = fmaf(bf2f((unsigned short)(rr[u].z & 0xFFFF)), hh[u], P2);
          P3 = fmaf(bf2f((unsigned short)((unsigned)rr[u].z >> 16)), hh[u], P3);
        }
      }
      for (; j < end; ++j) {
        int4 r0 = csr4[(size_t)j];
        float h0 = bf2f(h16[(size_t)r0.x * HID + d]);
        P0 = fmaf(bf2f((unsigned short)(r0.y & 0xFFFF)), h0, P0);
        P1 = fmaf(bf2f((unsigned short)((unsigned)r0.y >> 16)), h0, P1);
        P2 = fmaf(bf2f((unsigned short)(r0.z & 0xFFFF)), h0, P2);
        P3 = fmaf(bf2f((unsigned short)((unsigned)r0.z >> 16)), h0, P3);
      }
    }
    float acc = fmaf(P3, w3_, fmaf(P2, w2_, fmaf(P1, w1_, P0 * w0)));
    sagg[w * 4 + i][d] = acc;
  }
  __syncthreads();
  // ---- Phase B: MFMA node transform (m89 layouts, split-bf16) ----
  int l = tid & 63;
  int q = l & 15;
  int g = l >> 4;
  int node = base + q;
  if (node >= n) node = n - 1;   // clamp; stores guarded
  bf16x8 aghi[2], aglo[2], ahhi[2], ahlo[2];
#pragma unroll
  for (int kt = 0; kt < 2; ++kt) {
    int koff = kt * 32 + g * 8;
    const float* hp = h + (size_t)node * HID + koff;
    ahhi[kt] = *(const bf16x8*)(h16 + (size_t)node * HID + koff);
#pragma unroll
    for (int j = 0; j < 8; ++j) {
      float av = sagg[q][koff + j];
      unsigned short hi = f2bf(av);
      aghi[kt][j] = (short)hi;
      aglo[kt][j] = (short)f2bf(av - bf2f(hi));
      float r = hp[j] - bf2f((unsigned short)ahhi[kt][j]);
      ahlo[kt][j] = (short)f2bf(r);
    }
  }
  f32x4 aR = {0.f, 0.f, 0.f, 0.f};
  f32x4 aO = {0.f, 0.f, 0.f, 0.f};
  f32x4 aS = {0.f, 0.f, 0.f, 0.f};
#pragma unroll
  for (int kt = 0; kt < 2; ++kt) {
    int f = kt * 4 + w;
    const bf16x8* bRh = (const bf16x8*)(nwhi + (((size_t)0 * 8 + f) * 64 + l) * 8);
    const bf16x8* bRl = (const bf16x8*)(nwlo + (((size_t)0 * 8 + f) * 64 + l) * 8);
    const bf16x8* bOh = (const bf16x8*)(nwhi + (((size_t)1 * 8 + f) * 64 + l) * 8);
    const bf16x8* bOl = (const bf16x8*)(nwlo + (((size_t)1 * 8 + f) * 64 + l) * 8);
    const bf16x8* bSh = (const bf16x8*)(nwhi + (((size_t)2 * 8 + f) * 64 + l) * 8);
    const bf16x8* bSl = (const bf16x8*)(nwlo + (((size_t)2 * 8 + f) * 64 + l) * 8);
    aR = __builtin_amdgcn_mfma_f32_16x16x32_bf16(aglo[kt], *bRh, aR, 0, 0, 0);
    aR = __builtin_amdgcn_mfma_f32_16x16x32_bf16(aghi[kt], *bRl, aR, 0, 0, 0);
    aR = __builtin_amdgcn_mfma_f32_16x16x32_bf16(aghi[kt], *bRh, aR, 0, 0, 0);
    aO = __builtin_amdgcn_mfma_f32_16x16x32_bf16(ahlo[kt], *bOh, aO, 0, 0, 0);
    aO = __builtin_amdgcn_mfma_f32_16x16x32_bf16(ahhi[kt], *bOl, aO, 0, 0, 0);
    aO = __builtin_amdgcn_mfma_f32_16x16x32_bf16(ahhi[kt], *bOh, aO, 0, 0, 0);
    aS = __builtin_amdgcn_mfma_f32_16x16x32_bf16(ahlo[kt], *bSh, aS, 0, 0, 0);
    aS = __builtin_amdgcn_mfma_f32_16x16x32_bf16(ahhi[kt], *bSl, aS, 0, 0, 0);
    aS = __builtin_amdgcn_mfma_f32_16x16x32_bf16(ahhi[kt], *bSh, aS, 0, 0, 0);
  }
  int col = w * 16 + q;
  float bd = rel_b[col];
#pragma unroll
  for (int r = 0; r < 4; ++r) {
    int nd = base + g * 4 + r;
    if (nd < n) {
      float v = fmaxf(aR[r] + aO[r] + bd, 0.f) + aS[r];
      hn[(size_t)nd * HID + col] = v;
      hn16[(size_t)nd * HID + col] = f2bf(v);
    }
  }
}

// ---- MFMA head (r12-validated) ----
__global__ __launch_bounds__(256, 4)
void head_kernel(const float* __restrict__ h,
                 const unsigned short* __restrict__ h16,
                 const unsigned short* __restrict__ w1bhi,
                 const unsigned short* __restrict__ w1blo,
                 const float* __restrict__ b1,
                 const float* __restrict__ w2,
                 const float* __restrict__ b2,
                 float* __restrict__ out, int n) {
  __shared__ float red[4][16];
  int tid = threadIdx.x;
  int w = tid >> 6;
  int l = tid & 63;
  int row = l & 15;
  int g = l >> 4;
  int base = blockIdx.x * 16;
  int node = base + row;
  if (node >= n) node = n - 1;
  f32x4 acc[8];
#pragma unroll
  for (int t = 0; t < 8; ++t) acc[t] = (f32x4){0.f, 0.f, 0.f, 0.f};
#pragma unroll
  for (int kt = 0; kt < 2; ++kt) {
    int koff = kt * 32 + g * 8;
    bf16x8 ahi = *(const bf16x8*)(h16 + (size_t)node * HID + koff);
    const float* hp = h + (size_t)node * HID + koff;
    bf16x8 alo;
#pragma unroll
    for (int j = 0; j < 8; ++j) {
      float r = hp[j] - bf2f((unsigned short)ahi[j]);
      alo[j] = (short)f2bf(r);
    }
#pragma unroll
    for (int t = 0; t < 8; ++t) {
      int f = kt * 32 + w * 8 + t;
      bf16x8 bhi = *(const bf16x8*)(w1bhi + (size_t)f * 512 + l * 8);
      bf16x8 blo = *(const bf16x8*)(w1blo + (size_t)f * 512 + l * 8);
      acc[t] = __builtin_amdgcn_mfma_f32_16x16x32_bf16(alo, bhi, acc[t], 0, 0, 0);
      acc[t] = __builtin_amdgcn_mfma_f32_16x16x32_bf16(ahi, blo, acc[t], 0, 0, 0);
      acc[t] = __builtin_amdgcn_mfma_f32_16x16x32_bf16(ahi, bhi, acc[t], 0, 0, 0);
    }
  }
  float s0 = 0.f, s1 = 0.f, s2 = 0.f, s3 = 0.f;
#pragma unroll
  for (int t = 0; t < 8; ++t) {
    int ff = (w * 8 + t) * 16 + row;
    float bb = b1[ff];
    float ww = w2[ff];
    float xv, gl;
    xv = acc[t][0] + bb; gl = 0.5f * xv * (1.f + erff(xv * 0.70710678118654752f)); s0 = fmaf(gl, ww, s0);
    xv = acc[t][1] + bb; gl = 0.5f * xv * (1.f + erff(xv * 0.70710678118654752f)); s1 = fmaf(gl, ww, s1);
    xv = acc[t][2] + bb; gl = 0.5f * xv * (1.f + erff(xv * 0.70710678118654752f)); s2 = fmaf(gl, ww, s2);
    xv = acc[t][3] + bb; gl = 0.5f * xv * (1.f + erff(xv * 0.70710678118654752f)); s3 = fmaf(gl, ww, s3);
  }
#pragma unroll
  for (int off = 1; off < 16; off <<= 1) {
    s0 += __shfl_xor(s0, off);
    s1 += __shfl_xor(s1, off);
    s2 += __shfl_xor(s2, off);
    s3 += __shfl_xor(s3, off);
  }
  if ((l & 15) == 0) {
    red[w][g * 4 + 0] = s0;
    red[w][g * 4 + 1] = s1;
    red[w][g * 4 + 2] = s2;
    red[w][g * 4 + 3] = s3;
  }
  __syncthreads();
  if (tid < 16 && base + tid < n)
    out[base + tid] = red[0][tid] + red[1][tid] + red[2][tid] + red[3][tid] + b2[0];
}

extern "C" void kernel_launch(void* const* d_in, const int* in_sizes, int n_in,
                              void* d_out, int out_size, void* d_ws, size_t ws_size,
                              hipStream_t stream) {
  const int*   x          = (const int*)d_in[0];
  const int*   edge_index = (const int*)d_in[1];
  const float* edge_attr  = (const float*)d_in[2];
  const float* vert_emb   = (const float*)d_in[3];
  const float* edge_emb_w = (const float*)d_in[4];
  const float* edge_lin_w = (const float*)d_in[5];
  const float* rel_w      = (const float*)d_in[6];
  const float* rel_b      = (const float*)d_in[7];
  const float* root_w     = (const float*)d_in[8];
  const float* res_w      = (const float*)d_in[9];
  const float* w1         = (const float*)d_in[10];
  const float* b1         = (const float*)d_in[11];
  const float* w2         = (const float*)d_in[12];
  const float* b2         = (const float*)d_in[13];

  const int n = in_sizes[0];
  const int E = in_sizes[2] / 4;
  const int* src = edge_index;
  const int* dst = edge_index + E;
  const int nb = (n + 255) / 256;

  // workspace layout:
  //   Wl[2048] f | hA[n*64] f | hB[n*64] f | csr4[E] int4 |
  //   row_ptr[n+1] | cursor[n] | deg[n] | bsum[256] | boff[256] (ints) |
  //   (16B-align) w1bhi[32768] | w1blo[32768] | nwhi[61440] | nwlo[61440] |
  //   h16A[n*64] | h16B[n*64] (u16)
  float* ws   = (float*)d_ws;
  float* Wl   = ws;
  float* hA   = ws + 2048;
  float* hB   = hA + (size_t)n * HID;
  int4* csr4  = (int4*)(hB + (size_t)n * HID);
  int* row_ptr = (int*)(csr4 + (size_t)E);
  int* cursor  = row_ptr + (n + 1);
  int* deg     = cursor + n;
  int* bsum    = deg + n;
  int* boff    = bsum + 256;
  unsigned short* w1bhi = (unsigned short*)(((size_t)(boff + 256) + 15) & ~(size_t)15);
  unsigned short* w1blo = w1bhi + 64 * 512;
  unsigned short* nwhi  = w1blo + 64 * 512;
  unsigned short* nwlo  = nwhi + NLAY * 3 * 4096;
  unsigned short* h16A  = nwlo + NLAY * 3 * 4096;
  unsigned short* h16B  = h16A + (size_t)n * HID;

  prep_all_kernel<<<dim3(36), dim3(256), 0, stream>>>(
      edge_emb_w, edge_lin_w, w1, rel_w, root_w, res_w,
      Wl, w1bhi, w1blo, nwhi, nwlo);

  int totalHD = n * HID;
  embed_kernel<<<dim3((totalHD + 255) / 256), dim3(256), 0, stream>>>(
      x, vert_emb, hA, h16A, deg, n);

  hist_kernel<<<dim3((E + 255) / 256), dim3(256), 0, stream>>>(dst, deg, E);
  bsum_kernel<<<dim3(nb), dim3(256), 0, stream>>>(deg, bsum, n);
  bscan_kernel<<<dim3(1), dim3(256), 0, stream>>>(bsum, boff, nb);
  scan3_kernel<<<dim3(nb), dim3(256), 0, stream>>>(deg, boff, row_ptr, cursor, n);
  scatter_kernel<<<dim3((E + 255) / 256), dim3(256), 0, stream>>>(
      src, dst, (const float4*)edge_attr, cursor, csr4, E);

  float* hc = hA;
  float* hx = hB;
  unsigned short* h16c = h16A;
  unsigned short* h16x = h16B;
  for (int l = 0; l < NLAY; ++l) {
    layer_fused_kernel<<<dim3((n + 15) / 16), dim3(256), 0, stream>>>(
        row_ptr, csr4, Wl + l * 4 * HID, hc, h16c,
        nwhi + (size_t)l * 3 * 4096, nwlo + (size_t)l * 3 * 4096,
        rel_b + l * HID, hx, h16x, n);
    float* t = hc; hc = hx; hx = t;
    unsigned short* t16 = h16c; h16c = h16x; h16x = t16;
  }

  head_kernel<<<dim3((n + 15) / 16), dim3(256), 0, stream>>>(
      hc, h16c, w1bhi, w1blo, b1, w2, b2, (float*)d_out, n);
}